// Round 3
// baseline (2048.621 us; speedup 1.0000x reference)
//
#include <hip/hip_runtime.h>
#include <hip/hip_bf16.h>

#define HIDDEN  128
#define NUM_RBF 50
#define CUTOFF  5.0f

// width = CUTOFF/(NUM_RBF-1) = 5/49 ; inv_width = 49/5
#define INV_WIDTH (49.0f / 5.0f)
#define OFF_STEP  (5.0f / 49.0f)

__device__ __forceinline__ float silu(float x) {
    return x / (1.0f + __expf(-x));
}

// One block (128 threads) per edge. Accumulates f32 messages into agg
// (either d_ws scratch or d_out directly — both f32).
__global__ __launch_bounds__(HIDDEN) void edge_kernel(
    const float* __restrict__ h,
    const float* __restrict__ pos,
    const int* __restrict__ edge_index,
    const float* __restrict__ fw1,
    const float* __restrict__ fb1,
    const float* __restrict__ fw2,
    const float* __restrict__ fb2,
    float* __restrict__ agg,
    int n_nodes, int n_edges)
{
    const int e = blockIdx.x;
    const int j = threadIdx.x;           // hidden channel 0..127

    __shared__ float rbf_s[NUM_RBF];
    __shared__ float t_s[HIDDEN];

    int row = edge_index[e];
    int col = edge_index[n_edges + e];
    // Defensive clamp: any index surprise becomes finite error, not OOB.
    row = min(max(row, 0), n_nodes - 1);
    col = min(max(col, 0), n_nodes - 1);

    const float dx = pos[row * 3 + 0] - pos[col * 3 + 0];
    const float dy = pos[row * 3 + 1] - pos[col * 3 + 1];
    const float dz = pos[row * 3 + 2] - pos[col * 3 + 2];
    const float dist = sqrtf(dx * dx + dy * dy + dz * dz + 1e-8f);

    if (j < NUM_RBF) {
        const float x = (dist - OFF_STEP * (float)j) * INV_WIDTH;
        rbf_s[j] = __expf(-0.5f * x * x);
    }
    __syncthreads();

    // layer 1: rbf[50] @ fw1[50,128] + fb1 -> silu
    float acc = fb1[j];
#pragma unroll
    for (int k = 0; k < NUM_RBF; ++k)
        acc += rbf_s[k] * fw1[k * HIDDEN + j];
    t_s[j] = silu(acc);
    __syncthreads();

    // layer 2: t[128] @ fw2[128,128] + fb2
    float w = fb2[j];
#pragma unroll 8
    for (int k = 0; k < HIDDEN; ++k)
        w += t_s[k] * fw2[k * HIDDEN + j];

    const float cut = (dist <= CUTOFF)
                        ? 0.5f * (__cosf((float)M_PI * dist * (1.0f / CUTOFF)) + 1.0f)
                        : 0.0f;

    const float msg = h[col * HIDDEN + j] * (w * cut);
    atomicAdd(&agg[row * HIDDEN + j], msg);
}

// One block (128 threads) per node. agg may alias out: each block reads only
// its own node's row (into LDS, behind a barrier) before overwriting it, so
// in-place is race-free.
__global__ __launch_bounds__(HIDDEN) void node_kernel(
    const float* __restrict__ h,
    const float* __restrict__ agg,
    const float* __restrict__ iw1,
    const float* __restrict__ ib1,
    const float* __restrict__ iw2,
    const float* __restrict__ ib2,
    float* __restrict__ out)
{
    const int n = blockIdx.x;
    const int j = threadIdx.x;

    __shared__ float a_s[HIDDEN];
    __shared__ float t_s[HIDDEN];

    a_s[j] = agg[n * HIDDEN + j];
    __syncthreads();

    float acc = ib1[j];
#pragma unroll 8
    for (int k = 0; k < HIDDEN; ++k)
        acc += a_s[k] * iw1[k * HIDDEN + j];
    t_s[j] = silu(acc);
    __syncthreads();

    float o = ib2[j];
#pragma unroll 8
    for (int k = 0; k < HIDDEN; ++k)
        o += t_s[k] * iw2[k * HIDDEN + j];

    o += h[n * HIDDEN + j];
    out[n * HIDDEN + j] = o;
}

extern "C" void kernel_launch(void* const* d_in, const int* in_sizes, int n_in,
                              void* d_out, int out_size, void* d_ws, size_t ws_size,
                              hipStream_t stream)
{
    const float* h   = (const float*)d_in[0];
    const float* pos = (const float*)d_in[1];
    const int*   ei  = (const int*)d_in[2];
    const float* fw1 = (const float*)d_in[3];
    const float* fb1 = (const float*)d_in[4];
    const float* fw2 = (const float*)d_in[5];
    const float* fb2 = (const float*)d_in[6];
    const float* iw1 = (const float*)d_in[7];
    const float* ib1 = (const float*)d_in[8];
    const float* iw2 = (const float*)d_in[9];
    const float* ib2 = (const float*)d_in[10];
    float* out = (float*)d_out;

    const int n_nodes = in_sizes[0] / HIDDEN;
    const int n_edges = in_sizes[2] / 2;

    const size_t need = (size_t)n_nodes * HIDDEN * sizeof(float);
    const bool use_ws = (d_ws != nullptr) && (ws_size >= need);

    // agg buffer: prefer scratch; fall back to accumulating in d_out and
    // finishing the node MLP in place (race-free, see node_kernel).
    float* agg = use_ws ? (float*)d_ws : out;

    hipMemsetAsync(agg, 0, need, stream);

    edge_kernel<<<n_edges, HIDDEN, 0, stream>>>(h, pos, ei, fw1, fb1, fw2, fb2,
                                                agg, n_nodes, n_edges);

    node_kernel<<<n_nodes, HIDDEN, 0, stream>>>(h, agg, iw1, ib1, iw2, ib2, out);
}

// Round 4
// 886.960 us; speedup vs baseline: 2.3097x; 2.3097x over previous
//
#include <hip/hip_runtime.h>
#include <hip/hip_bf16.h>

#define HIDDEN  128
#define NUM_RBF 50
#define CUTOFF  5.0f
#define INV_WIDTH (49.0f / 5.0f)
#define OFF_STEP  (5.0f / 49.0f)
#define PI_F 3.14159265358979f

// LDS row strides (halfs). 136 = 128+8: rows 16B-aligned (272 B), and
// fragment reads land 2-way bank-aliased (free per m136).
#define PK2 136
#define PT  136

typedef __attribute__((ext_vector_type(8))) short short8;   // 8 bf16 (4 VGPR)
typedef __attribute__((ext_vector_type(4))) float floatx4;  // MFMA acc

__device__ __forceinline__ unsigned short f2bf(float x) {
    union { float f; unsigned int u; } v; v.f = x;
    // round-to-nearest-even (our values are never NaN/inf)
    return (unsigned short)((v.u + 0x7fff + ((v.u >> 16) & 1)) >> 16);
}

__device__ __forceinline__ float silu(float x) {
    return x / (1.0f + __expf(-x));
}

// 256 threads = 4 waves; each wave processes 16-edge tiles (grid-stride).
// fw2 staged once/block in LDS (bf16, transposed, padded); fw1 fragments and
// biases live in registers. 48 MFMAs per 16 edges.
__global__ __launch_bounds__(256) void edge_mfma_kernel(
    const float* __restrict__ h,
    const float* __restrict__ pos,
    const int* __restrict__ ei,
    const float* __restrict__ fw1,
    const float* __restrict__ fb1,
    const float* __restrict__ fw2,
    const float* __restrict__ fb2,
    float* __restrict__ agg,
    int n_nodes, int n_edges)
{
    __shared__ __attribute__((aligned(16))) unsigned short fw2T[128 * PK2];
    __shared__ __attribute__((aligned(16))) unsigned short tbuf[4 * 16 * PT];
    __shared__ int   s_row[4][16];
    __shared__ int   s_col[4][16];
    __shared__ float s_cut[4][16];

    const int tid  = threadIdx.x;
    const int wave = tid >> 6;
    const int lane = tid & 63;
    const int l15  = lane & 15;
    const int quad = lane >> 4;

    // ---- stage fw2 (transposed, bf16) into LDS: fw2T[n][k] = fw2[k][n] ----
    for (int idx = tid; idx < HIDDEN * HIDDEN; idx += 256) {
        const int k = idx >> 7, n = idx & 127;
        fw2T[n * PK2 + k] = f2bf(fw2[idx]);
    }

    // ---- preload fw1 B-fragments into registers (zero rows k>=50) ----
    // B-frag mapping (16x16x32): lane holds B[k = kiter*32 + quad*8 + j][n = l15 + 16*nt]
    short8 b1[2][8];
#pragma unroll
    for (int kit = 0; kit < 2; ++kit)
#pragma unroll
        for (int nt = 0; nt < 8; ++nt) {
            short8 f;
#pragma unroll
            for (int j = 0; j < 8; ++j) {
                const int k = kit * 32 + quad * 8 + j;
                const int n = nt * 16 + l15;
                f[j] = (k < NUM_RBF) ? (short)f2bf(fw1[k * HIDDEN + n]) : (short)0;
            }
            b1[kit][nt] = f;
        }

    float fb1v[8], fb2v[8];
#pragma unroll
    for (int nt = 0; nt < 8; ++nt) {
        fb1v[nt] = fb1[nt * 16 + l15];
        fb2v[nt] = fb2[nt * 16 + l15];
    }

    __syncthreads();   // fw2T visible to all waves; no barriers inside loop

    unsigned short* twave = &tbuf[wave * 16 * PT];
    const int tiles = (n_edges + 15) >> 4;

    for (int tile = blockIdx.x * 4 + wave; tile < tiles; tile += gridDim.x * 4) {
        // ---- per-edge meta: lane computes for edge m = l15 (x4 redundant) ----
        const int e = tile * 16 + l15;
        const bool valid = (e < n_edges);
        int row = valid ? ei[e] : 0;
        int col = valid ? ei[n_edges + e] : 0;
        row = min(max(row, 0), n_nodes - 1);
        col = min(max(col, 0), n_nodes - 1);
        const float dx = pos[row * 3 + 0] - pos[col * 3 + 0];
        const float dy = pos[row * 3 + 1] - pos[col * 3 + 1];
        const float dz = pos[row * 3 + 2] - pos[col * 3 + 2];
        const float dist = sqrtf(dx * dx + dy * dy + dz * dz + 1e-8f);
        const float cut = (valid && dist <= CUTOFF)
            ? 0.5f * (__cosf(PI_F * dist * (1.0f / CUTOFF)) + 1.0f) : 0.0f;
        if (lane < 16) {
            s_row[wave][l15] = row; s_col[wave][l15] = col; s_cut[wave][l15] = cut;
        }

        // ---- A1 fragments computed analytically (RBF values, bf16) ----
        // A-frag mapping: lane holds A[m = l15][k = kiter*32 + quad*8 + j]
        short8 a1[2];
#pragma unroll
        for (int kit = 0; kit < 2; ++kit) {
            short8 f;
#pragma unroll
            for (int j = 0; j < 8; ++j) {
                const int k = kit * 32 + quad * 8 + j;
                const float x = (dist - OFF_STEP * (float)k) * INV_WIDTH;
                const float rv = (k < NUM_RBF) ? __expf(-0.5f * x * x) : 0.0f;
                f[j] = (short)f2bf(rv);
            }
            a1[kit] = f;
        }

        // ---- layer 1: [16x64]@[64x128] + b -> silu -> tbuf (bf16) ----
        // C/D mapping: value r sits at [m = quad*4 + r][n = nt*16 + l15]
#pragma unroll
        for (int nt = 0; nt < 8; ++nt) {
            floatx4 c = {fb1v[nt], fb1v[nt], fb1v[nt], fb1v[nt]};
            c = __builtin_amdgcn_mfma_f32_16x16x32_bf16(a1[0], b1[0][nt], c, 0, 0, 0);
            c = __builtin_amdgcn_mfma_f32_16x16x32_bf16(a1[1], b1[1][nt], c, 0, 0, 0);
#pragma unroll
            for (int r = 0; r < 4; ++r) {
                const int m = quad * 4 + r;
                twave[m * PT + nt * 16 + l15] = f2bf(silu(c[r]));
            }
        }

        // ---- A2 fragments from tbuf (ds_read_b128, 16B-aligned) ----
        short8 a2[4];
#pragma unroll
        for (int kit = 0; kit < 4; ++kit)
            a2[kit] = *(const short8*)&twave[l15 * PT + kit * 32 + quad * 8];

        int mrow[4], mcol[4]; float mcut[4];
#pragma unroll
        for (int r = 0; r < 4; ++r) {
            const int m = quad * 4 + r;
            mrow[r] = s_row[wave][m]; mcol[r] = s_col[wave][m]; mcut[r] = s_cut[wave][m];
        }

        // ---- layer 2: [16x128]@[128x128] + b, fused cutoff*h epilogue ----
#pragma unroll
        for (int nt = 0; nt < 8; ++nt) {
            floatx4 c = {fb2v[nt], fb2v[nt], fb2v[nt], fb2v[nt]};
#pragma unroll
            for (int kit = 0; kit < 4; ++kit) {
                const short8 b =
                    *(const short8*)&fw2T[(nt * 16 + l15) * PK2 + kit * 32 + quad * 8];
                c = __builtin_amdgcn_mfma_f32_16x16x32_bf16(a2[kit], b, c, 0, 0, 0);
            }
            const int chan = nt * 16 + l15;
#pragma unroll
            for (int r = 0; r < 4; ++r) {
                const float w   = c[r] * mcut[r];
                const float val = w * h[mcol[r] * HIDDEN + chan];
                atomicAdd(&agg[mrow[r] * HIDDEN + chan], val);
            }
        }
    }
}

// One block (128 threads) per node. agg may alias out: each block reads only
// its own node's row (into LDS, behind a barrier) before overwriting it.
__global__ __launch_bounds__(HIDDEN) void node_kernel(
    const float* __restrict__ h,
    const float* __restrict__ agg,
    const float* __restrict__ iw1,
    const float* __restrict__ ib1,
    const float* __restrict__ iw2,
    const float* __restrict__ ib2,
    float* __restrict__ out)
{
    const int n = blockIdx.x;
    const int j = threadIdx.x;

    __shared__ float a_s[HIDDEN];
    __shared__ float t_s[HIDDEN];

    a_s[j] = agg[n * HIDDEN + j];
    __syncthreads();

    float acc = ib1[j];
#pragma unroll 8
    for (int k = 0; k < HIDDEN; ++k)
        acc += a_s[k] * iw1[k * HIDDEN + j];
    t_s[j] = silu(acc);
    __syncthreads();

    float o = ib2[j];
#pragma unroll 8
    for (int k = 0; k < HIDDEN; ++k)
        o += t_s[k] * iw2[k * HIDDEN + j];

    o += h[n * HIDDEN + j];
    out[n * HIDDEN + j] = o;
}

extern "C" void kernel_launch(void* const* d_in, const int* in_sizes, int n_in,
                              void* d_out, int out_size, void* d_ws, size_t ws_size,
                              hipStream_t stream)
{
    const float* h   = (const float*)d_in[0];
    const float* pos = (const float*)d_in[1];
    const int*   ei  = (const int*)d_in[2];
    const float* fw1 = (const float*)d_in[3];
    const float* fb1 = (const float*)d_in[4];
    const float* fw2 = (const float*)d_in[5];
    const float* fb2 = (const float*)d_in[6];
    const float* iw1 = (const float*)d_in[7];
    const float* ib1 = (const float*)d_in[8];
    const float* iw2 = (const float*)d_in[9];
    const float* ib2 = (const float*)d_in[10];
    float* out = (float*)d_out;

    const int n_nodes = in_sizes[0] / HIDDEN;
    const int n_edges = in_sizes[2] / 2;

    const size_t need = (size_t)n_nodes * HIDDEN * sizeof(float);
    const bool use_ws = (d_ws != nullptr) && (ws_size >= need);
    float* agg = use_ws ? (float*)d_ws : out;   // fallback: accumulate in out

    hipMemsetAsync(agg, 0, need, stream);

    edge_mfma_kernel<<<1024, 256, 0, stream>>>(h, pos, ei, fw1, fb1, fw2, fb2,
                                               agg, n_nodes, n_edges);

    node_kernel<<<n_nodes, HIDDEN, 0, stream>>>(h, agg, iw1, ib1, iw2, ib2, out);
}

// Round 5
// 474.543 us; speedup vs baseline: 4.3170x; 1.8691x over previous
//
#include <hip/hip_runtime.h>
#include <hip/hip_bf16.h>

#define HIDDEN  128
#define NUM_RBF 50
#define CUTOFF  5.0f
#define INV_WIDTH (49.0f / 5.0f)
#define OFF_STEP  (5.0f / 49.0f)
#define PI_F 3.14159265358979f

// LDS row stride (halfs). 136 = 128+8: rows 16B-aligned (272 B) and fragment
// reads land 2-way bank-aliased (free per m136).
#define PK2 136
#define PT  136

typedef __attribute__((ext_vector_type(8))) short short8;   // 8 bf16 (4 VGPR)
typedef __attribute__((ext_vector_type(4))) float floatx4;  // MFMA acc

__device__ __forceinline__ unsigned short f2bf(float x) {
    union { float f; unsigned int u; } v; v.f = x;
    return (unsigned short)((v.u + 0x7fff + ((v.u >> 16) & 1)) >> 16);  // RNE
}

__device__ __forceinline__ float silu(float x) {
    return x / (1.0f + __expf(-x));
}

// ---------------------------------------------------------------------------
// Edge kernel: 256 thr = 4 waves, each wave owns 16-edge tiles (grid-stride).
// fw2 staged once/block in LDS; fw1 frags + biases in registers. Edge meta
// broadcast via shfl; h gather issued at tile start to hide latency.
// ---------------------------------------------------------------------------
__global__ __launch_bounds__(256) void edge_mfma_kernel(
    const float* __restrict__ h,
    const float* __restrict__ pos,
    const int* __restrict__ ei,
    const float* __restrict__ fw1,
    const float* __restrict__ fb1,
    const float* __restrict__ fw2,
    const float* __restrict__ fb2,
    float* __restrict__ agg,
    int n_nodes, int n_edges)
{
    __shared__ __attribute__((aligned(16))) unsigned short fw2T[128 * PK2];
    __shared__ __attribute__((aligned(16))) unsigned short tbuf[4 * 16 * PT];

    const int tid  = threadIdx.x;
    const int wave = tid >> 6;
    const int lane = tid & 63;
    const int l15  = lane & 15;
    const int quad = lane >> 4;

    // stage fw2 transposed (bf16): fw2T[n][k] = fw2[k][n]
    for (int idx = tid; idx < HIDDEN * HIDDEN; idx += 256) {
        const int k = idx >> 7, n = idx & 127;
        fw2T[n * PK2 + k] = f2bf(fw2[idx]);
    }

    // fw1 B-fragments in registers (zero rows k>=50)
    short8 b1[2][8];
#pragma unroll
    for (int kit = 0; kit < 2; ++kit)
#pragma unroll
        for (int nt = 0; nt < 8; ++nt) {
            short8 f;
#pragma unroll
            for (int j = 0; j < 8; ++j) {
                const int k = kit * 32 + quad * 8 + j;
                const int n = nt * 16 + l15;
                f[j] = (k < NUM_RBF) ? (short)f2bf(fw1[k * HIDDEN + n]) : (short)0;
            }
            b1[kit][nt] = f;
        }

    float fb1v[8], fb2v[8];
#pragma unroll
    for (int nt = 0; nt < 8; ++nt) {
        fb1v[nt] = fb1[nt * 16 + l15];
        fb2v[nt] = fb2[nt * 16 + l15];
    }

    __syncthreads();   // fw2T ready; no barriers inside the loop

    unsigned short* twave = &tbuf[wave * 16 * PT];
    const int tiles = (n_edges + 15) >> 4;

    for (int tile = blockIdx.x * 4 + wave; tile < tiles; tile += gridDim.x * 4) {
        // ---- edge meta: lane handles edge m = l15 (x4 redundant) ----
        const int e = tile * 16 + l15;
        const bool valid = (e < n_edges);
        int row = ei[valid ? e : 0];
        int col = ei[n_edges + (valid ? e : 0)];
        row = min(max(row, 0), n_nodes - 1);
        col = min(max(col, 0), n_nodes - 1);
        const float dx = pos[row * 3 + 0] - pos[col * 3 + 0];
        const float dy = pos[row * 3 + 1] - pos[col * 3 + 1];
        const float dz = pos[row * 3 + 2] - pos[col * 3 + 2];
        const float dist = sqrtf(dx * dx + dy * dy + dz * dz + 1e-8f);
        const float cut = (valid && dist <= CUTOFF)
            ? 0.5f * (__cosf(PI_F * dist * (1.0f / CUTOFF)) + 1.0f) : 0.0f;

        // broadcast to C-layout owners (m = quad*4 + r) via shfl, no LDS
        int mrow[4], mcol[4]; float mcut[4];
#pragma unroll
        for (int r = 0; r < 4; ++r) {
            const int src = quad * 4 + r;      // lanes 0..15 hold edges 0..15
            mrow[r] = __shfl(row, src);
            mcol[r] = __shfl(col, src);
            mcut[r] = __shfl(cut, src);
        }

        // ---- EARLY h gather (consumed only in the epilogue) ----
        float hv[4][8];
#pragma unroll
        for (int r = 0; r < 4; ++r)
#pragma unroll
            for (int nt = 0; nt < 8; ++nt)
                hv[r][nt] = h[mcol[r] * HIDDEN + nt * 16 + l15];

        // ---- A1 fragments: RBFs computed analytically in-register ----
        short8 a1[2];
#pragma unroll
        for (int kit = 0; kit < 2; ++kit) {
            short8 f;
#pragma unroll
            for (int j = 0; j < 8; ++j) {
                const int k = kit * 32 + quad * 8 + j;
                const float x = (dist - OFF_STEP * (float)k) * INV_WIDTH;
                const float rv = (k < NUM_RBF) ? __expf(-0.5f * x * x) : 0.0f;
                f[j] = (short)f2bf(rv);
            }
            a1[kit] = f;
        }

        // ---- layer 1 -> silu -> tbuf (bf16) ----
#pragma unroll
        for (int nt = 0; nt < 8; ++nt) {
            floatx4 c = {fb1v[nt], fb1v[nt], fb1v[nt], fb1v[nt]};
            c = __builtin_amdgcn_mfma_f32_16x16x32_bf16(a1[0], b1[0][nt], c, 0, 0, 0);
            c = __builtin_amdgcn_mfma_f32_16x16x32_bf16(a1[1], b1[1][nt], c, 0, 0, 0);
#pragma unroll
            for (int r = 0; r < 4; ++r)
                twave[(quad * 4 + r) * PT + nt * 16 + l15] = f2bf(silu(c[r]));
        }

        // ---- A2 fragments from tbuf ----
        short8 a2[4];
#pragma unroll
        for (int kit = 0; kit < 4; ++kit)
            a2[kit] = *(const short8*)&twave[l15 * PT + kit * 32 + quad * 8];

        // ---- layer 2 + fused cutoff*h epilogue + atomic scatter ----
#pragma unroll
        for (int nt = 0; nt < 8; ++nt) {
            floatx4 c = {fb2v[nt], fb2v[nt], fb2v[nt], fb2v[nt]};
#pragma unroll
            for (int kit = 0; kit < 4; ++kit) {
                const short8 b =
                    *(const short8*)&fw2T[(nt * 16 + l15) * PK2 + kit * 32 + quad * 8];
                c = __builtin_amdgcn_mfma_f32_16x16x32_bf16(a2[kit], b, c, 0, 0, 0);
            }
            const int chan = nt * 16 + l15;
#pragma unroll
            for (int r = 0; r < 4; ++r) {
                const float val = c[r] * mcut[r] * hv[r][nt];
                atomicAdd(&agg[mrow[r] * HIDDEN + chan], val);
            }
        }
    }
}

// ---------------------------------------------------------------------------
// Node kernel (MFMA): out = h + silu(agg@iw1+b1)@iw2+b2.
// iw1 fragments in registers (128 VGPR), iw2 staged in LDS. Persistent grid.
// Safe when agg aliases out: each wave reads its tile's agg rows before
// writing those same rows, no cross-tile overlap.
// ---------------------------------------------------------------------------
__global__ __launch_bounds__(256) void node_mfma_kernel(
    const float* __restrict__ h,
    const float* __restrict__ agg,
    const float* __restrict__ iw1,
    const float* __restrict__ ib1,
    const float* __restrict__ iw2,
    const float* __restrict__ ib2,
    float* __restrict__ out,
    int n_nodes)
{
    __shared__ __attribute__((aligned(16))) unsigned short w2T[128 * PK2];
    __shared__ __attribute__((aligned(16))) unsigned short tbuf[4 * 16 * PT];

    const int tid  = threadIdx.x;
    const int wave = tid >> 6;
    const int lane = tid & 63;
    const int l15  = lane & 15;
    const int quad = lane >> 4;

    for (int idx = tid; idx < HIDDEN * HIDDEN; idx += 256) {
        const int k = idx >> 7, n = idx & 127;
        w2T[n * PK2 + k] = f2bf(iw2[idx]);
    }

    // iw1 B-fragments in registers: lane holds B[k=kit*32+quad*8+j][n=nt*16+l15]
    short8 b1[4][8];
#pragma unroll
    for (int kit = 0; kit < 4; ++kit)
#pragma unroll
        for (int nt = 0; nt < 8; ++nt) {
            short8 f;
#pragma unroll
            for (int j = 0; j < 8; ++j) {
                const int k = kit * 32 + quad * 8 + j;
                f[j] = (short)f2bf(iw1[k * HIDDEN + nt * 16 + l15]);
            }
            b1[kit][nt] = f;
        }

    float ib1v[8], ib2v[8];
#pragma unroll
    for (int nt = 0; nt < 8; ++nt) {
        ib1v[nt] = ib1[nt * 16 + l15];
        ib2v[nt] = ib2[nt * 16 + l15];
    }

    __syncthreads();

    unsigned short* twave = &tbuf[wave * 16 * PT];
    const int tiles = (n_nodes + 15) >> 4;

    for (int tile = blockIdx.x * 4 + wave; tile < tiles; tile += gridDim.x * 4) {
        const int m0 = tile * 16;

        // A1 fragments from agg (f32, coalesced) -> bf16
        const int mA = min(m0 + l15, n_nodes - 1);
        short8 a1[4];
#pragma unroll
        for (int kit = 0; kit < 4; ++kit) {
            const float* p = &agg[mA * HIDDEN + kit * 32 + quad * 8];
            short8 f;
#pragma unroll
            for (int j = 0; j < 8; ++j) f[j] = (short)f2bf(p[j]);
            a1[kit] = f;
        }

        // prefetch residual h for the rows this lane will write
        int mo[4]; float hres[4][8];
#pragma unroll
        for (int r = 0; r < 4; ++r) {
            mo[r] = m0 + quad * 4 + r;
            const int mc = min(mo[r], n_nodes - 1);
#pragma unroll
            for (int nt = 0; nt < 8; ++nt)
                hres[r][nt] = h[mc * HIDDEN + nt * 16 + l15];
        }

        // layer 1 -> silu -> tbuf
#pragma unroll
        for (int nt = 0; nt < 8; ++nt) {
            floatx4 c = {ib1v[nt], ib1v[nt], ib1v[nt], ib1v[nt]};
#pragma unroll
            for (int kit = 0; kit < 4; ++kit)
                c = __builtin_amdgcn_mfma_f32_16x16x32_bf16(a1[kit], b1[kit][nt], c, 0, 0, 0);
#pragma unroll
            for (int r = 0; r < 4; ++r)
                twave[(quad * 4 + r) * PT + nt * 16 + l15] = f2bf(silu(c[r]));
        }

        short8 a2[4];
#pragma unroll
        for (int kit = 0; kit < 4; ++kit)
            a2[kit] = *(const short8*)&twave[l15 * PT + kit * 32 + quad * 8];

        // layer 2 + residual + store
#pragma unroll
        for (int nt = 0; nt < 8; ++nt) {
            floatx4 c = {ib2v[nt], ib2v[nt], ib2v[nt], ib2v[nt]};
#pragma unroll
            for (int kit = 0; kit < 4; ++kit) {
                const short8 b =
                    *(const short8*)&w2T[(nt * 16 + l15) * PK2 + kit * 32 + quad * 8];
                c = __builtin_amdgcn_mfma_f32_16x16x32_bf16(a2[kit], b, c, 0, 0, 0);
            }
            const int chan = nt * 16 + l15;
#pragma unroll
            for (int r = 0; r < 4; ++r)
                if (mo[r] < n_nodes)
                    out[mo[r] * HIDDEN + chan] = hres[r][nt] + c[r];
        }
    }
}

extern "C" void kernel_launch(void* const* d_in, const int* in_sizes, int n_in,
                              void* d_out, int out_size, void* d_ws, size_t ws_size,
                              hipStream_t stream)
{
    const float* h   = (const float*)d_in[0];
    const float* pos = (const float*)d_in[1];
    const int*   ei  = (const int*)d_in[2];
    const float* fw1 = (const float*)d_in[3];
    const float* fb1 = (const float*)d_in[4];
    const float* fw2 = (const float*)d_in[5];
    const float* fb2 = (const float*)d_in[6];
    const float* iw1 = (const float*)d_in[7];
    const float* ib1 = (const float*)d_in[8];
    const float* iw2 = (const float*)d_in[9];
    const float* ib2 = (const float*)d_in[10];
    float* out = (float*)d_out;

    const int n_nodes = in_sizes[0] / HIDDEN;
    const int n_edges = in_sizes[2] / 2;

    const size_t need = (size_t)n_nodes * HIDDEN * sizeof(float);
    const bool use_ws = (d_ws != nullptr) && (ws_size >= need);
    float* agg = use_ws ? (float*)d_ws : out;   // fallback: accumulate in out

    hipMemsetAsync(agg, 0, need, stream);

    // 1536 = 2 exact rounds of the 768 resident blocks (3/CU, 52 KB LDS)
    edge_mfma_kernel<<<1536, 256, 0, stream>>>(h, pos, ei, fw1, fb1, fw2, fb2,
                                               agg, n_nodes, n_edges);

    node_mfma_kernel<<<512, 256, 0, stream>>>(h, agg, iw1, ib1, iw2, ib2, out,
                                              n_nodes);
}